// Round 2
// baseline (1028.953 us; speedup 1.0000x reference)
//
#include <hip/hip_runtime.h>
#include <hip/hip_bf16.h>
#include <math.h>

#define B_ 256
#define D_ 128
#define T_ 64
#define H_ 256
#define F_ 16
#define XCOLS 1040  // 4*H + F ; layout: [i(256) | ste(256) | c(256) | o(256) | fre(16)]

__device__ __forceinline__ float hsig(float x) {
    return fminf(fmaxf(fmaf(x, 0.16666667f, 0.5f), 0.0f), 1.0f);
}

// ---------------------------------------------------------------------------
// Kernel A: xproj[t][b][col] = bias[col] + sum_d xs[t][b][d] * Wcat[d][col]
// xs[t][b][d] = input_x[b][d*T + t]
// grid = 64 t * 16 bgroups = 1024 blocks, 256 threads. Each block: 16 batch rows.
// ---------------------------------------------------------------------------
__global__ __launch_bounds__(256) void xproj_kernel(
    const float* __restrict__ input_x,
    const float* __restrict__ W_i,   const float* __restrict__ b_i,
    const float* __restrict__ W_ste, const float* __restrict__ b_ste,
    const float* __restrict__ W_c,   const float* __restrict__ b_c,
    const float* __restrict__ W_o,   const float* __restrict__ b_o,
    const float* __restrict__ W_fre, const float* __restrict__ b_fre,
    float* __restrict__ xp)
{
    __shared__ float xt[16][128];
    const int tid = threadIdx.x;
    const int bx  = blockIdx.x;
    const int t   = bx >> 4;   // [0,64)
    const int bg  = bx & 15;   // [0,16)

    // load x tile [16 rows][128 d]   (strided gather; input is small & L2-resident)
    for (int i = tid; i < 16 * 128; i += 256) {
        int r = i >> 7, d = i & 127;
        xt[r][d] = input_x[(size_t)(bg * 16 + r) * (D_ * T_) + (d << 6) + t];
    }
    __syncthreads();

    const int j  = tid;        // output column within each gate block
    const int jf = j & 15;     // fre column (computed redundantly by all threads)

    float acc[16][4];
#pragma unroll
    for (int r = 0; r < 16; r++) { acc[r][0] = 0.f; acc[r][1] = 0.f; acc[r][2] = 0.f; acc[r][3] = 0.f; }
    float accf[16];
#pragma unroll
    for (int r = 0; r < 16; r++) accf[r] = 0.f;

    for (int d = 0; d < 128; d++) {
        float w0 = W_i  [d * 256 + j];
        float w1 = W_ste[d * 256 + j];
        float w2 = W_c  [d * 256 + j];
        float w3 = W_o  [d * 256 + j];
        float wf = W_fre[d * 16 + jf];
#pragma unroll
        for (int r = 0; r < 16; r++) {
            float xv = xt[r][d];
            acc[r][0] = fmaf(xv, w0, acc[r][0]);
            acc[r][1] = fmaf(xv, w1, acc[r][1]);
            acc[r][2] = fmaf(xv, w2, acc[r][2]);
            acc[r][3] = fmaf(xv, w3, acc[r][3]);
            accf[r]   = fmaf(xv, wf, accf[r]);
        }
    }

    const float bi = b_i[j], bs = b_ste[j], bc = b_c[j], bo = b_o[j];
    const float bf = b_fre[jf];
    const size_t rowbase = ((size_t)t * B_ + (size_t)bg * 16) * XCOLS;
#pragma unroll
    for (int r = 0; r < 16; r++) {
        size_t base = rowbase + (size_t)r * XCOLS;
        xp[base + j]         = acc[r][0] + bi;
        xp[base + 256 + j]   = acc[r][1] + bs;
        xp[base + 512 + j]   = acc[r][2] + bc;
        xp[base + 768 + j]   = acc[r][3] + bo;
        if (j < 16) xp[base + 1024 + j] = accf[r] + bf;
    }
}

// ---------------------------------------------------------------------------
// Kernel B: the sequential scan. One block per batch row; thread j owns hidden
// unit j (S_re/S_im[16] in registers), h lives in LDS.
// ---------------------------------------------------------------------------
__global__ __launch_bounds__(256) void scan_kernel(
    const float* __restrict__ xp,
    const float* __restrict__ U_i, const float* __restrict__ U_ste,
    const float* __restrict__ U_c, const float* __restrict__ U_o,
    const float* __restrict__ U_fre,
    const float* __restrict__ U_a, const float* __restrict__ b_a,
    const float* __restrict__ W_p, const float* __restrict__ b_p,
    const float* __restrict__ fc_w, const float* __restrict__ fc_b,
    float* __restrict__ out)
{
    __shared__ float h_lds[256];
    __shared__ float fre_lds[16];
    __shared__ float tabc[16], tabs[16];
    __shared__ float red[256];

    const int j  = threadIdx.x;
    const int b  = blockIdx.x;
    const int jf = j & 15;

    h_lds[j] = 0.0f;
    if (j < 16) {
        // omega mod 2*pi = 2*pi*m/16, m = (t*f) mod 16  (t integer, freq = f/16)
        tabc[j] = cosf((float)(M_PI / 8.0) * (float)j);
        tabs[j] = sinf((float)(M_PI / 8.0) * (float)j);
    }

    float Sre[16], Sim[16];
#pragma unroll
    for (int f = 0; f < 16; f++) { Sre[f] = 0.f; Sim[f] = 0.f; }
    float ua[16];
#pragma unroll
    for (int f = 0; f < 16; f++) ua[f] = U_a[f];
    const float ba = b_a[j];
    __syncthreads();

    for (int t = 0; t < T_; t++) {
        const float* xrow = xp + ((size_t)t * B_ + b) * XCOLS;

        // 5 matvecs against h (reads h_lds; U streamed from L2)
        float acc_i = 0.f, acc_s = 0.f, acc_c = 0.f, acc_o = 0.f, acc_f = 0.f;
#pragma unroll 4
        for (int k = 0; k < 256; k++) {
            float hk = h_lds[k];
            acc_i = fmaf(hk, U_i  [(k << 8) + j],  acc_i);
            acc_s = fmaf(hk, U_ste[(k << 8) + j],  acc_s);
            acc_c = fmaf(hk, U_c  [(k << 8) + j],  acc_c);
            acc_o = fmaf(hk, U_o  [(k << 8) + j],  acc_o);
            acc_f = fmaf(hk, U_fre[(k << 4) + jf], acc_f);
        }

        float gi = hsig(xrow[j]        + acc_i);
        float gs = hsig(xrow[256 + j]  + acc_s);
        float gf = hsig(xrow[1024 + jf] + acc_f);
        float cc = gi * tanhf(xrow[512 + j] + acc_c);
        float go = hsig(xrow[768 + j]  + acc_o);

        if (j < 16) fre_lds[j] = gf;
        __syncthreads();   // matvec reads of h done; fre published

        const int tp = t + 1;
        float accA = 0.f;
#pragma unroll
        for (int f = 0; f < 16; f++) {
            int m = (tp * f) & 15;
            float re = tabc[m], im = tabs[m];
            float ff = gs * fre_lds[f];
            Sre[f] = ff * Sre[f] + cc * re;
            Sim[f] = ff * Sim[f] + cc * im;
            float Af = fmaf(Sre[f], Sre[f], Sim[f] * Sim[f]);
            accA = fmaf(Af, ua[f], accA);
        }
        float a    = tanhf(accA + ba);
        float hnew = go * a;

        h_lds[j] = hnew;   // safe: all matvec reads completed at the barrier above
        __syncthreads();   // h ready for next step
    }

    // epilogue: out[b] = (sum_j h_j * W_p[j] + b_p) * fc_w + fc_b
    red[j] = h_lds[j] * W_p[j];
    __syncthreads();
    for (int s = 128; s > 0; s >>= 1) {
        if (j < s) red[j] += red[j + s];
        __syncthreads();
    }
    if (j == 0) out[b] = (red[0] + b_p[0]) * fc_w[0] + fc_b[0];
}

// ---------------------------------------------------------------------------
extern "C" void kernel_launch(void* const* d_in, const int* in_sizes, int n_in,
                              void* d_out, int out_size, void* d_ws, size_t ws_size,
                              hipStream_t stream) {
    const float* input_x = (const float*)d_in[0];
    const float* W_i   = (const float*)d_in[1];
    const float* U_i   = (const float*)d_in[2];
    const float* b_i   = (const float*)d_in[3];
    const float* W_ste = (const float*)d_in[4];
    const float* U_ste = (const float*)d_in[5];
    const float* b_ste = (const float*)d_in[6];
    const float* W_fre = (const float*)d_in[7];
    const float* U_fre = (const float*)d_in[8];
    const float* b_fre = (const float*)d_in[9];
    const float* W_c   = (const float*)d_in[10];
    const float* U_c   = (const float*)d_in[11];
    const float* b_c   = (const float*)d_in[12];
    const float* W_o   = (const float*)d_in[13];
    const float* U_o   = (const float*)d_in[14];
    const float* b_o   = (const float*)d_in[15];
    const float* U_a   = (const float*)d_in[16];
    const float* b_a   = (const float*)d_in[17];
    const float* W_p   = (const float*)d_in[18];
    const float* b_p   = (const float*)d_in[19];
    const float* fc_w  = (const float*)d_in[20];
    const float* fc_b  = (const float*)d_in[21];

    float* xp  = (float*)d_ws;            // [T][B][1040] f32 = 68.2 MB
    float* out = (float*)d_out;           // [B] f32

    xproj_kernel<<<dim3(T_ * 16), dim3(256), 0, stream>>>(
        input_x, W_i, b_i, W_ste, b_ste, W_c, b_c, W_o, b_o, W_fre, b_fre, xp);

    scan_kernel<<<dim3(B_), dim3(256), 0, stream>>>(
        xp, U_i, U_ste, U_c, U_o, U_fre, U_a, b_a, W_p, b_p, fc_w, fc_b, out);
}

// Round 7
// 713.563 us; speedup vs baseline: 1.4420x; 1.4420x over previous
//
#include <hip/hip_runtime.h>
#include <hip/hip_bf16.h>
#include <hip/hip_fp16.h>
#include <math.h>

#define B_ 256
#define D_ 128
#define T_ 64
#define H_ 256
#define F_ 16
#define GCOLS 1024   // 4 gates * 256, interleaved [j][4] = (i,ste,c,o)

// Workspace layout — total EXACTLY 68,157,440 B (= R2's proven-working footprint):
//   xpg : f32  [T][B][256][4]  = 67,108,864 B   (gate-interleaved projections)
//   xpf : f16  [T][B][16]      =    524,288 B   (fre projections)
//   Upk : f16  [256][256][4]   =    524,288 B   (gate-interleaved recurrent U)
#define XPG_OFF 0
#define XPF_OFF 67108864
#define UPK_OFF 67633152

__device__ __forceinline__ float hsig(float x) {
    return fminf(fmaxf(fmaf(x, 0.16666667f, 0.5f), 0.0f), 1.0f);
}

// ---------------------------------------------------------------------------
// Kernel A: gate projections, gate-interleaved f32; fre projections fp16.
// xs[t][b][d] = input_x[b][d*T + t]
// ---------------------------------------------------------------------------
__global__ __launch_bounds__(256) void xproj_kernel(
    const float* __restrict__ input_x,
    const float* __restrict__ W_i,   const float* __restrict__ b_i,
    const float* __restrict__ W_ste, const float* __restrict__ b_ste,
    const float* __restrict__ W_c,   const float* __restrict__ b_c,
    const float* __restrict__ W_o,   const float* __restrict__ b_o,
    const float* __restrict__ W_fre, const float* __restrict__ b_fre,
    float* __restrict__ xpg, __half* __restrict__ xpf)
{
    __shared__ float xt[16][128];
    const int tid = threadIdx.x;
    const int bx  = blockIdx.x;
    const int t   = bx >> 4;
    const int bg  = bx & 15;

    for (int i = tid; i < 16 * 128; i += 256) {
        int r = i >> 7, d = i & 127;
        xt[r][d] = input_x[(size_t)(bg * 16 + r) * (D_ * T_) + (d << 6) + t];
    }
    __syncthreads();

    const int j  = tid;
    const int jf = j & 15;

    float acc[16][4];
#pragma unroll
    for (int r = 0; r < 16; r++) { acc[r][0] = 0.f; acc[r][1] = 0.f; acc[r][2] = 0.f; acc[r][3] = 0.f; }
    float accf[16];
#pragma unroll
    for (int r = 0; r < 16; r++) accf[r] = 0.f;

    for (int d = 0; d < 128; d++) {
        float w0 = W_i  [d * 256 + j];
        float w1 = W_ste[d * 256 + j];
        float w2 = W_c  [d * 256 + j];
        float w3 = W_o  [d * 256 + j];
        float wf = W_fre[d * 16 + jf];
#pragma unroll
        for (int r = 0; r < 16; r++) {
            float xv = xt[r][d];
            acc[r][0] = fmaf(xv, w0, acc[r][0]);
            acc[r][1] = fmaf(xv, w1, acc[r][1]);
            acc[r][2] = fmaf(xv, w2, acc[r][2]);
            acc[r][3] = fmaf(xv, w3, acc[r][3]);
            accf[r]   = fmaf(xv, wf, accf[r]);
        }
    }

    const float bi = b_i[j], bs = b_ste[j], bc = b_c[j], bo = b_o[j];
    const float bf = b_fre[jf];
    const size_t row0 = (size_t)t * B_ + (size_t)bg * 16;
#pragma unroll
    for (int r = 0; r < 16; r++) {
        const size_t row = row0 + r;
        float4 v = make_float4(acc[r][0] + bi, acc[r][1] + bs,
                               acc[r][2] + bc, acc[r][3] + bo);
        *(float4*)(xpg + row * GCOLS + (j << 2)) = v;
        if (j < 16) xpf[row * 16 + j] = __float2half(accf[r] + bf);
    }
}

// ---------------------------------------------------------------------------
// Kernel P: pack recurrent gate weights to fp16, gate-interleaved [k][j][4].
// ---------------------------------------------------------------------------
__global__ __launch_bounds__(256) void pack_kernel(
    const float* __restrict__ U_i, const float* __restrict__ U_ste,
    const float* __restrict__ U_c, const float* __restrict__ U_o,
    __half* __restrict__ Upk)
{
    const int k = blockIdx.x, j = threadIdx.x;
    const int idx = (k << 8) + j;
    __half* dst = Upk + ((size_t)idx << 2);
    dst[0] = __float2half(U_i  [idx]);
    dst[1] = __float2half(U_ste[idx]);
    dst[2] = __float2half(U_c  [idx]);
    dst[3] = __float2half(U_o  [idx]);
}

// ---------------------------------------------------------------------------
// Kernel B: scan. One block / batch row, 512 threads: j = tid&255 owns hidden
// column j; half = tid>>8 splits the k-sum. U fp16 packed; accum f32.
// ---------------------------------------------------------------------------
__global__ __launch_bounds__(512) void scan_kernel(
    const float* __restrict__ xpg, const __half* __restrict__ xpf,
    const __half* __restrict__ Upk,
    const float* __restrict__ U_fre,
    const float* __restrict__ U_a, const float* __restrict__ b_a,
    const float* __restrict__ W_p, const float* __restrict__ b_p,
    const float* __restrict__ fc_w, const float* __restrict__ fc_b,
    float* __restrict__ out)
{
    __shared__ float h_lds[256];
    __shared__ float fre_w[256 * 16];   // U_fre f32, 16 KB
    __shared__ float red5[5][256];      // cross-half partials
    __shared__ float fre_lds[16];
    __shared__ float tabc[16], tabs[16];

    const int tid  = threadIdx.x;
    const int j    = tid & 255;
    const int half = tid >> 8;
    const int kbase = half << 7;        // 0 or 128
    const int b    = blockIdx.x;
    const int jf   = j & 15;

    if (tid < 256) h_lds[tid] = 0.0f;
    if (tid < 16) {
        tabc[tid] = cosf((float)(M_PI / 8.0) * (float)tid);
        tabs[tid] = sinf((float)(M_PI / 8.0) * (float)tid);
    }
    // stage U_fre (f32 input) -> LDS
    for (int i = tid; i < 256 * 16; i += 512)
        fre_w[i] = U_fre[i];

    float Sre[16], Sim[16];
#pragma unroll
    for (int f = 0; f < 16; f++) { Sre[f] = 0.f; Sim[f] = 0.f; }
    float ua[16];
#pragma unroll
    for (int f = 0; f < 16; f++) ua[f] = U_a[f];
    const float ba = b_a[j];
    __syncthreads();

    for (int t = 0; t < T_; t++) {
        const size_t row = (size_t)t * B_ + b;

        // prefetch xproj values (independent of k-loop)
        float x_i = 0.f, x_s = 0.f, x_c = 0.f, x_o = 0.f, x_f = 0.f;
        if (half == 0) {
            float4 xv = *(const float4*)(xpg + row * GCOLS + (j << 2));
            x_i = xv.x; x_s = xv.y; x_c = xv.z; x_o = xv.w;
            x_f = __half2float(xpf[row * 16 + jf]);
        }

        float a0 = 0.f, a1 = 0.f, a2 = 0.f, a3 = 0.f, af = 0.f;
#pragma unroll 8
        for (int kk = 0; kk < 128; kk++) {
            const int k = kbase + kk;
            const float hk = h_lds[k];
            union { uint2 u; __half2 h2[2]; } w;
            w.u = *(const uint2*)(Upk + ((((size_t)k << 8) + j) << 2));
            a0 = fmaf(__low2float (w.h2[0]), hk, a0);
            a1 = fmaf(__high2float(w.h2[0]), hk, a1);
            a2 = fmaf(__low2float (w.h2[1]), hk, a2);
            a3 = fmaf(__high2float(w.h2[1]), hk, a3);
            af = fmaf(fre_w[(k << 4) + jf],  hk, af);
        }

        if (half == 1) {
            red5[0][j] = a0; red5[1][j] = a1; red5[2][j] = a2;
            red5[3][j] = a3; red5[4][j] = af;
        }
        __syncthreads();   // partials ready; all h_lds reads complete

        float gs = 0.f, cc = 0.f, go = 0.f;
        if (half == 0) {
            a0 += red5[0][j]; a1 += red5[1][j]; a2 += red5[2][j];
            a3 += red5[3][j]; af += red5[4][j];
            float gi = hsig(x_i + a0);
            gs = hsig(x_s + a1);
            cc = gi * tanhf(x_c + a2);
            go = hsig(x_o + a3);
            float gf = hsig(x_f + af);
            if (j < 16) fre_lds[j] = gf;
        }
        __syncthreads();   // fre_lds ready

        if (half == 0) {
            const int tp = t + 1;
            float accA = 0.f;
#pragma unroll
            for (int f = 0; f < 16; f++) {
                int m = (tp * f) & 15;
                float re = tabc[m], im = tabs[m];
                float ff = gs * fre_lds[f];
                Sre[f] = ff * Sre[f] + cc * re;
                Sim[f] = ff * Sim[f] + cc * im;
                float Af = fmaf(Sre[f], Sre[f], Sim[f] * Sim[f]);
                accA = fmaf(Af, ua[f], accA);
            }
            float a    = tanhf(accA + ba);
            h_lds[j]   = go * a;
        }
        __syncthreads();   // h ready for next step
    }

    // epilogue: out[b] = (sum_j h_j * W_p[j] + b_p) * fc_w + fc_b
    float* redf = &red5[0][0];
    if (half == 0) redf[j] = h_lds[j] * W_p[j];
    __syncthreads();
    for (int s = 128; s > 0; s >>= 1) {
        if (half == 0 && j < s) redf[j] += redf[j + s];
        __syncthreads();
    }
    if (tid == 0) out[b] = (redf[0] + b_p[0]) * fc_w[0] + fc_b[0];
}

// ---------------------------------------------------------------------------
extern "C" void kernel_launch(void* const* d_in, const int* in_sizes, int n_in,
                              void* d_out, int out_size, void* d_ws, size_t ws_size,
                              hipStream_t stream) {
    const float* input_x = (const float*)d_in[0];
    const float* W_i   = (const float*)d_in[1];
    const float* U_i   = (const float*)d_in[2];
    const float* b_i   = (const float*)d_in[3];
    const float* W_ste = (const float*)d_in[4];
    const float* U_ste = (const float*)d_in[5];
    const float* b_ste = (const float*)d_in[6];
    const float* W_fre = (const float*)d_in[7];
    const float* U_fre = (const float*)d_in[8];
    const float* b_fre = (const float*)d_in[9];
    const float* W_c   = (const float*)d_in[10];
    const float* U_c   = (const float*)d_in[11];
    const float* b_c   = (const float*)d_in[12];
    const float* W_o   = (const float*)d_in[13];
    const float* U_o   = (const float*)d_in[14];
    const float* b_o   = (const float*)d_in[15];
    const float* U_a   = (const float*)d_in[16];
    const float* b_a   = (const float*)d_in[17];
    const float* W_p   = (const float*)d_in[18];
    const float* b_p   = (const float*)d_in[19];
    const float* fc_w  = (const float*)d_in[20];
    const float* fc_b  = (const float*)d_in[21];

    char* ws = (char*)d_ws;
    float*  xpg = (float*)(ws + XPG_OFF);
    __half* xpf = (__half*)(ws + XPF_OFF);
    __half* Upk = (__half*)(ws + UPK_OFF);
    float* out = (float*)d_out;

    pack_kernel<<<dim3(256), dim3(256), 0, stream>>>(U_i, U_ste, U_c, U_o, Upk);

    xproj_kernel<<<dim3(T_ * 16), dim3(256), 0, stream>>>(
        input_x, W_i, b_i, W_ste, b_ste, W_c, b_c, W_o, b_o, W_fre, b_fre,
        xpg, xpf);

    scan_kernel<<<dim3(B_), dim3(512), 0, stream>>>(
        xpg, xpf, Upk, U_fre, U_a, b_a, W_p, b_p, fc_w, fc_b, out);
}